// Round 8
// baseline (1193.252 us; speedup 1.0000x reference)
//
#include <hip/hip_runtime.h>
#include <hip/hip_bf16.h>

#define EPSF 1e-5f
#define BB 2
#define CC 3
#define HH 48
#define WW 48
#define SS 2304
#define DD 64
#define NHH 8
#define FFF 2048
#define NLL 8
#define KS 21
#define PP 441
#define NROW (BB*SS)      // 4608
#define KSPLIT 16
#define KB (SS/KSPLIT)    // 144
#define FFSPLIT 8
#define FFCHUNK (FFF/FFSPLIT)   // 256

// ---------------- conv3x3 + batchnorm + relu -> y[b,s,d] ----------------
__global__ __launch_bounds__(256) void k_conv(const float* __restrict__ x,
    const float* __restrict__ cw, const float* __restrict__ cb,
    const float* __restrict__ bng, const float* __restrict__ bnb,
    const float* __restrict__ bnm, const float* __restrict__ bnv,
    float* __restrict__ y)
{
  int tid = blockIdx.x * 256 + threadIdx.x;      // B*S*64 = 294912 threads
  int d = tid & 63;
  int s = (tid >> 6) % SS;
  int b = tid / (SS * 64);
  int h = s / WW, w = s % WW;
  float acc = cb[d];
  #pragma unroll
  for (int c = 0; c < 3; ++c) {
    #pragma unroll
    for (int kh = 0; kh < 3; ++kh) {
      int ih = h + kh - 1;
      if (ih < 0 || ih >= HH) continue;
      #pragma unroll
      for (int kw = 0; kw < 3; ++kw) {
        int iw = w + kw - 1;
        if (iw < 0 || iw >= WW) continue;
        acc = fmaf(x[((b*3 + c)*HH + ih)*WW + iw],
                   cw[((d*3 + c)*3 + kh)*3 + kw], acc);
      }
    }
  }
  acc = (acc - bnm[d]) * rsqrtf(bnv[d] + EPSF) * bng[d] + bnb[d];
  acc = fmaxf(acc, 0.f);
  y[(size_t)(b*SS + s)*DD + d] = acc;
}

// ------- 32-row-tile GEMM: out[n,j] = bias[j] + sum_k A[n,k]*W[j,k] -------
__global__ __launch_bounds__(256) void k_gemm32(const float* __restrict__ A,
    const float* __restrict__ Wt, const float* __restrict__ bias,
    float* __restrict__ out, int K, int J)
{
  __shared__ float As[64][36];   // As[k][m], m in 0..31
  __shared__ float Ws[64][68];   // Ws[k][j]
  int tid = threadIdx.x;
  int m0 = blockIdx.x * 32;
  int j0 = blockIdx.y * 64;
  int tx = tid & 15, ty = tid >> 4;
  float acc[2][4] = {};
  for (int k0 = 0; k0 < K; k0 += 64) {
    #pragma unroll
    for (int i = 0; i < 8; ++i) {
      int idx = tid + i * 256;
      int m = idx >> 6, k = idx & 63;
      As[k][m] = A[(size_t)(m0 + m) * K + k0 + k];
    }
    #pragma unroll
    for (int i = 0; i < 16; ++i) {
      int idx = tid + i * 256;
      int j = idx >> 6, k = idx & 63;
      int jj = j0 + j;
      Ws[k][j] = (jj < J) ? Wt[(size_t)jj * K + k0 + k] : 0.f;
    }
    __syncthreads();
    #pragma unroll 8
    for (int k = 0; k < 64; ++k) {
      float2 af = *(const float2*)&As[k][ty * 2];
      float4 wf = *(const float4*)&Ws[k][tx * 4];
      float a[2] = {af.x, af.y};
      float w[4] = {wf.x, wf.y, wf.z, wf.w};
      #pragma unroll
      for (int i = 0; i < 2; ++i)
        #pragma unroll
        for (int j = 0; j < 4; ++j)
          acc[i][j] = fmaf(a[i], w[j], acc[i][j]);
    }
    __syncthreads();
  }
  #pragma unroll
  for (int i = 0; i < 2; ++i) {
    int m = m0 + ty * 2 + i;
    #pragma unroll
    for (int j = 0; j < 4; ++j) {
      int jj = j0 + tx * 4 + j;
      if (jj >= J) continue;
      out[(size_t)m * J + jj] = acc[i][j] + bias[jj];
    }
  }
}

// -- out-proj GEMM (K=J=64, 32-row tile) fused with residual + LayerNorm1 --
__global__ __launch_bounds__(256) void k_oproj_ln(const float* __restrict__ o,
    const float* __restrict__ Wt, const float* __restrict__ bias,
    float* __restrict__ y, const float* __restrict__ g, const float* __restrict__ bb)
{
  __shared__ float As[64][36];   // As[k][m] = o[m0+m][k]
  __shared__ float Ws[64][68];   // Ws[k][j] = Wt[j][k]
  int tid = threadIdx.x;
  int m0 = blockIdx.x * 32;
  int tx = tid & 15, ty = tid >> 4;
  #pragma unroll
  for (int i = 0; i < 8; ++i) {
    int idx = tid + i * 256;
    int m = idx >> 6, k = idx & 63;
    As[k][m] = o[(size_t)(m0 + m) * DD + k];
  }
  #pragma unroll
  for (int i = 0; i < 16; ++i) {
    int idx = tid + i * 256;
    int j = idx >> 6, k = idx & 63;
    Ws[k][j] = Wt[(size_t)j * DD + k];
  }
  __syncthreads();
  float acc[2][4] = {};
  #pragma unroll 8
  for (int k = 0; k < 64; ++k) {
    float2 af = *(const float2*)&As[k][ty * 2];
    float4 wf = *(const float4*)&Ws[k][tx * 4];
    float a[2] = {af.x, af.y};
    float w[4] = {wf.x, wf.y, wf.z, wf.w};
    #pragma unroll
    for (int i = 0; i < 2; ++i)
      #pragma unroll
      for (int j = 0; j < 4; ++j)
        acc[i][j] = fmaf(a[i], w[j], acc[i][j]);
  }
  float4 gv = *(const float4*)&g[tx * 4];
  float4 bv = *(const float4*)&bb[tx * 4];
  float4 biv = *(const float4*)&bias[tx * 4];
  float gg[4] = {gv.x, gv.y, gv.z, gv.w};
  float bbv[4] = {bv.x, bv.y, bv.z, bv.w};
  float bi[4] = {biv.x, biv.y, biv.z, biv.w};
  #pragma unroll
  for (int i = 0; i < 2; ++i) {
    int m = m0 + ty * 2 + i;
    float4 yv = *(const float4*)&y[(size_t)m * DD + tx * 4];
    float yr[4] = {yv.x, yv.y, yv.z, yv.w};
    float z[4], s = 0.f, ss = 0.f;
    #pragma unroll
    for (int j = 0; j < 4; ++j) {
      float v = acc[i][j] + bi[j] + yr[j];
      z[j] = v; s += v; ss = fmaf(v, v, ss);
    }
    #pragma unroll
    for (int off = 1; off < 16; off <<= 1) {
      s  += __shfl_xor(s, off);
      ss += __shfl_xor(ss, off);
    }
    float mean = s * 0.015625f;
    float var = ss * 0.015625f - mean * mean;
    float inv = rsqrtf(var + EPSF);
    float4 ov;
    ov.x = (z[0] - mean) * inv * gg[0] + bbv[0];
    ov.y = (z[1] - mean) * inv * gg[1] + bbv[1];
    ov.z = (z[2] - mean) * inv * gg[2] + bbv[2];
    ov.w = (z[3] - mean) * inv * gg[3] + bbv[3];
    *(float4*)&y[(size_t)m * DD + tx * 4] = ov;
  }
}

// ---- fused FF, 32-row x 256-FF tiles: pff[split] = relu(y@W1^T+b1)@W2^T ----
// grid (144, FFSPLIT). LDS 52KB -> 3 blocks/CU.
__global__ __launch_bounds__(256) void k_ff(const float* __restrict__ y,
    const float* __restrict__ w1, const float* __restrict__ b1,
    const float* __restrict__ w2, float* __restrict__ pff)
{
  __shared__ float As[64][36];    // As[k][m]   = y[m0+m][k], m 0..31
  __shared__ float W1s[64][68];   // W1s[k][jf] = w1[ff0+jf][k]
  __shared__ float W2s[64][68];   // W2s[kf][j] = w2[j][ff0+kf]
  __shared__ float Hs[64][36];    // Hs[kf][m]  = relu activations
  int tid = threadIdx.x;
  int m0 = blockIdx.x * 32;
  int split = blockIdx.y;
  int tx = tid & 15, ty = tid >> 4;
  #pragma unroll
  for (int i = 0; i < 8; ++i) {
    int idx = tid + i * 256;
    int m = idx >> 6, k = idx & 63;
    As[k][m] = y[(size_t)(m0 + m) * DD + k];
  }
  float acc2[2][4] = {};
  for (int c = 0; c < FFCHUNK / 64; ++c) {
    int ff0 = split * FFCHUNK + c * 64;
    __syncthreads();   // As ready (c=0); prev chunk's W2s/Hs reads done
    #pragma unroll
    for (int i = 0; i < 16; ++i) {
      int idx = tid + i * 256;
      int jf = idx >> 6, k = idx & 63;
      W1s[k][jf] = w1[(size_t)(ff0 + jf) * DD + k];
      W2s[k][jf] = w2[(size_t)jf * FFF + ff0 + k];
    }
    __syncthreads();
    float acc1[2][4] = {};
    #pragma unroll 8
    for (int k = 0; k < 64; ++k) {
      float2 af = *(const float2*)&As[k][ty * 2];
      float4 wf = *(const float4*)&W1s[k][tx * 4];
      float a[2] = {af.x, af.y};
      float w[4] = {wf.x, wf.y, wf.z, wf.w};
      #pragma unroll
      for (int i = 0; i < 2; ++i)
        #pragma unroll
        for (int j = 0; j < 4; ++j)
          acc1[i][j] = fmaf(a[i], w[j], acc1[i][j]);
    }
    #pragma unroll
    for (int j = 0; j < 4; ++j) {
      float bj = b1[ff0 + tx * 4 + j];
      float2 hv;
      hv.x = fmaxf(acc1[0][j] + bj, 0.f);
      hv.y = fmaxf(acc1[1][j] + bj, 0.f);
      *(float2*)&Hs[tx * 4 + j][ty * 2] = hv;   // Hs[kf][m]
    }
    __syncthreads();
    #pragma unroll 8
    for (int k = 0; k < 64; ++k) {
      float2 hf = *(const float2*)&Hs[k][ty * 2];
      float4 wf = *(const float4*)&W2s[k][tx * 4];
      float h[2] = {hf.x, hf.y};
      float w[4] = {wf.x, wf.y, wf.z, wf.w};
      #pragma unroll
      for (int i = 0; i < 2; ++i)
        #pragma unroll
        for (int j = 0; j < 4; ++j)
          acc2[i][j] = fmaf(h[i], w[j], acc2[i][j]);
    }
  }
  #pragma unroll
  for (int i = 0; i < 2; ++i) {
    int m = m0 + ty * 2 + i;
    float4 ov = make_float4(acc2[i][0], acc2[i][1], acc2[i][2], acc2[i][3]);
    *(float4*)&pff[((size_t)split * NROW + m) * DD + tx * 4] = ov;
  }
}

// ---- reduce FF partials + b2 + residual + LayerNorm2, one wave per row ----
__global__ __launch_bounds__(256) void k_ff_reduce(const float* __restrict__ pff,
    const float* __restrict__ b2, float* __restrict__ y,
    const float* __restrict__ g, const float* __restrict__ bb)
{
  int lane = threadIdx.x & 63;
  int row = blockIdx.x * 4 + (threadIdx.x >> 6);
  float f = b2[lane];
  #pragma unroll
  for (int sp = 0; sp < FFSPLIT; ++sp)
    f += pff[((size_t)sp * NROW + row) * DD + lane];
  size_t base = (size_t)row * DD + lane;
  float z = y[base] + f;
  float s = z;
  #pragma unroll
  for (int off = 32; off; off >>= 1) s += __shfl_xor(s, off);
  float mean = s * 0.015625f;
  float dz = z - mean;
  float sq = dz * dz;
  #pragma unroll
  for (int off = 32; off; off >>= 1) sq += __shfl_xor(sq, off);
  float var = sq * 0.015625f;
  y[base] = dz * rsqrtf(var + EPSF) * g[lane] + bb[lane];
}

// ------- split-K attention, branchless (|scores| ~ O(1)), 3 queries/thread ----
// grid (bh=16, qtile=3, split=16); K/V tile of 144 staged in LDS.
__global__ __launch_bounds__(256) void k_attn(const float* __restrict__ qkv,
    float* __restrict__ pl, float* __restrict__ pacc)
{
  int bh = blockIdx.x; int b = bh >> 3; int hh = bh & 7;
  int split = blockIdx.z;
  __shared__ float kl[KB][8];
  __shared__ float vl[KB][8];
  int tid = threadIdx.x;
  for (int t = tid; t < KB * 4; t += 256) {
    int row = t >> 2, seg = t & 3;
    const float* base = qkv + (size_t)(b * SS + split * KB + row) * 192 + hh * 8;
    if (seg < 2) *(float4*)&kl[row][seg * 4]       = *(const float4*)(base + 64 + seg * 4);
    else         *(float4*)&vl[row][(seg - 2) * 4] = *(const float4*)(base + 128 + (seg - 2) * 4);
  }
  __syncthreads();

  const float sc = 0.3535533905932738f;  // 1/sqrt(8)
  float q[3][8], acc[3][8] = {}, l[3] = {};
  #pragma unroll
  for (int r = 0; r < 3; ++r) {
    int qi = blockIdx.y * 768 + r * 256 + tid;
    const float* qp = qkv + (size_t)(b * SS + qi) * 192 + hh * 8;
    float4 qa = *(const float4*)qp;
    float4 qb = *(const float4*)(qp + 4);
    q[r][0] = qa.x * sc; q[r][1] = qa.y * sc; q[r][2] = qa.z * sc; q[r][3] = qa.w * sc;
    q[r][4] = qb.x * sc; q[r][5] = qb.y * sc; q[r][6] = qb.z * sc; q[r][7] = qb.w * sc;
  }

  #pragma unroll 2
  for (int j = 0; j < KB; ++j) {
    float4 k0 = *(const float4*)&kl[j][0];
    float4 k1 = *(const float4*)&kl[j][4];
    float4 v0 = *(const float4*)&vl[j][0];
    float4 v1 = *(const float4*)&vl[j][4];
    #pragma unroll
    for (int r = 0; r < 3; ++r) {
      float s = q[r][0] * k0.x;
      s = fmaf(q[r][1], k0.y, s); s = fmaf(q[r][2], k0.z, s); s = fmaf(q[r][3], k0.w, s);
      s = fmaf(q[r][4], k1.x, s); s = fmaf(q[r][5], k1.y, s);
      s = fmaf(q[r][6], k1.z, s); s = fmaf(q[r][7], k1.w, s);
      float p = __expf(s);
      l[r] += p;
      acc[r][0] = fmaf(p, v0.x, acc[r][0]); acc[r][1] = fmaf(p, v0.y, acc[r][1]);
      acc[r][2] = fmaf(p, v0.z, acc[r][2]); acc[r][3] = fmaf(p, v0.w, acc[r][3]);
      acc[r][4] = fmaf(p, v1.x, acc[r][4]); acc[r][5] = fmaf(p, v1.y, acc[r][5]);
      acc[r][6] = fmaf(p, v1.z, acc[r][6]); acc[r][7] = fmaf(p, v1.w, acc[r][7]);
    }
  }
  #pragma unroll
  for (int r = 0; r < 3; ++r) {
    int qi = blockIdx.y * 768 + r * 256 + tid;
    size_t pidx = ((size_t)split * 16 + bh) * SS + qi;
    pl[pidx] = l[r];
    float4* pa = (float4*)(pacc + pidx * 8);
    pa[0] = make_float4(acc[r][0], acc[r][1], acc[r][2], acc[r][3]);
    pa[1] = make_float4(acc[r][4], acc[r][5], acc[r][6], acc[r][7]);
  }
}

__global__ __launch_bounds__(256) void k_attn_combine(const float* __restrict__ pl,
    const float* __restrict__ pacc, float* __restrict__ o)
{
  int idx = blockIdx.x * 256 + threadIdx.x;   // 16*2304 = 36864
  int bh = idx / SS; int qi = idx % SS;
  int b = bh >> 3, hh = bh & 7;
  float L = 0.f, acc[8] = {};
  #pragma unroll
  for (int sp = 0; sp < KSPLIT; ++sp) {
    size_t pidx = ((size_t)sp * 16 + bh) * SS + qi;
    L += pl[pidx];
    const float4* pa = (const float4*)(pacc + pidx * 8);
    float4 a0 = pa[0], a1 = pa[1];
    acc[0] += a0.x; acc[1] += a0.y; acc[2] += a0.z; acc[3] += a0.w;
    acc[4] += a1.x; acc[5] += a1.y; acc[6] += a1.z; acc[7] += a1.w;
  }
  float inv = 1.f / L;
  float* op = o + (size_t)(b * SS + qi) * DD + hh * 8;
  #pragma unroll
  for (int d = 0; d < 8; ++d) op[d] = acc[d] * inv;
}

// ---------------- softmax over 441 logits; probs fp32 in-place + fp32 kernel_out^T
__global__ __launch_bounds__(256) void k_softmax(float* __restrict__ logits,
    float* __restrict__ kout)
{
  __shared__ float red[8];
  int row = blockIdx.x;               // b*S + s
  int b = row / SS, s = row % SS;
  float* lp = logits + (size_t)row * PP;
  int t = threadIdx.x;
  float v0 = (t < PP) ? lp[t] : -1e30f;
  float v1 = (t + 256 < PP) ? lp[t + 256] : -1e30f;
  float mx = fmaxf(v0, v1);
  #pragma unroll
  for (int off = 32; off; off >>= 1) mx = fmaxf(mx, __shfl_xor(mx, off));
  if ((t & 63) == 0) red[t >> 6] = mx;
  __syncthreads();
  mx = fmaxf(fmaxf(red[0], red[1]), fmaxf(red[2], red[3]));
  float e0 = (t < PP) ? __expf(v0 - mx) : 0.f;
  float e1 = (t + 256 < PP) ? __expf(v1 - mx) : 0.f;
  float sm = e0 + e1;
  #pragma unroll
  for (int off = 32; off; off >>= 1) sm += __shfl_xor(sm, off);
  if ((t & 63) == 0) red[4 + (t >> 6)] = sm;
  __syncthreads();
  float inv = 1.f / (red[4] + red[5] + red[6] + red[7]);
  if (t < PP) {
    float p = e0 * inv;
    lp[t] = p;
    kout[(size_t)(b * PP + t) * SS + s] = p;
  }
  if (t + 256 < PP) {
    float p = e1 * inv;
    lp[t + 256] = p;
    kout[(size_t)(b * PP + t + 256) * SS + s] = p;
  }
}

// ------- final 21x21 reflect-padded gather: one wave per output pixel -------
__global__ __launch_bounds__(256) void k_gather(const float* __restrict__ x,
    const float* __restrict__ probs, float* __restrict__ out)
{
  int lane = threadIdx.x & 63;
  int pix = blockIdx.x * 4 + (threadIdx.x >> 6);  // 0..13823
  int w = pix % WW;
  int h = (pix / WW) % HH;
  int c = (pix / (WW * HH)) % CC;
  int b = pix / (WW * HH * CC);
  int s = h * WW + w;
  const float* pp = probs + (size_t)(b * SS + s) * PP;
  const float* xb = x + (size_t)(b * CC + c) * HH * WW;
  float acc = 0.f;
  for (int t = lane; t < PP; t += 64) {
    int kr = t / KS, kc = t - kr * KS;
    int ih = h + kr - 10;
    ih = (ih < 0) ? -ih : (ih > 47 ? 94 - ih : ih);
    int iw = w + kc - 10;
    iw = (iw < 0) ? -iw : (iw > 47 ? 94 - iw : iw);
    acc = fmaf(xb[ih * WW + iw], pp[t], acc);
  }
  #pragma unroll
  for (int off = 32; off; off >>= 1) acc += __shfl_xor(acc, off);
  if (lane == 0) out[pix] = acc;
}

extern "C" void kernel_launch(void* const* d_in, const int* in_sizes, int n_in,
                              void* d_out, int out_size, void* d_ws, size_t ws_size,
                              hipStream_t stream)
{
  (void)in_sizes; (void)n_in; (void)out_size; (void)ws_size;
  const float* x       = (const float*)d_in[0];
  const float* conv1_w = (const float*)d_in[1];
  const float* conv1_b = (const float*)d_in[2];
  const float* bn_g    = (const float*)d_in[3];
  const float* bn_b    = (const float*)d_in[4];
  const float* bn_m    = (const float*)d_in[5];
  const float* bn_v    = (const float*)d_in[6];
  const float* w_in    = (const float*)d_in[7];
  const float* b_in    = (const float*)d_in[8];
  const float* w_out   = (const float*)d_in[9];
  const float* b_out   = (const float*)d_in[10];
  const float* w1      = (const float*)d_in[11];
  const float* b1      = (const float*)d_in[12];
  const float* w2      = (const float*)d_in[13];
  const float* b2      = (const float*)d_in[14];
  const float* ln1g    = (const float*)d_in[15];
  const float* ln1b    = (const float*)d_in[16];
  const float* ln2g    = (const float*)d_in[17];
  const float* ln2b    = (const float*)d_in[18];
  const float* lw      = (const float*)d_in[19];
  const float* lb      = (const float*)d_in[20];

  // workspace: ~26 MiB
  float* y    = (float*)d_ws;      // 294912
  float* qkv  = y + 294912;        // 884736
  float* o    = qkv + 884736;      // 294912
  float* sc   = o + 294912;        // union region: 4718592 floats
  float* pacc = sc;                // attn acc partials: 16*16*2304*8 = 4718592
  float* pff  = sc;                // FF partials: 8*4608*64 = 2359296
  float* logits = sc;              // 4608*441 = 2032128
  float* pl   = sc + 4718592;      // attn l partials: 16*16*2304 = 589824

  float* out0 = (float*)d_out;
  float* kout = out0 + (size_t)BB * CC * HH * WW;

  k_conv<<<1152, 256, 0, stream>>>(x, conv1_w, conv1_b, bn_g, bn_b, bn_m, bn_v, y);

  for (int l = 0; l < NLL; ++l) {
    k_gemm32<<<dim3(144, 3), 256, 0, stream>>>(y, w_in + (size_t)l * 192 * 64,
        b_in + l * 192, qkv, 64, 192);
    k_attn<<<dim3(16, 3, KSPLIT), 256, 0, stream>>>(qkv, pl, pacc);
    k_attn_combine<<<144, 256, 0, stream>>>(pl, pacc, o);
    k_oproj_ln<<<144, 256, 0, stream>>>(o, w_out + (size_t)l * 64 * 64,
        b_out + l * 64, y, ln1g + l * 64, ln1b + l * 64);
    k_ff<<<dim3(144, FFSPLIT), 256, 0, stream>>>(y, w1 + (size_t)l * FFF * DD,
        b1 + (size_t)l * FFF, w2 + (size_t)l * DD * FFF, pff);
    k_ff_reduce<<<1152, 256, 0, stream>>>(pff, b2 + l * DD, y,
        ln2g + l * 64, ln2b + l * 64);
  }

  k_gemm32<<<dim3(144, 7), 256, 0, stream>>>(y, lw, lb, logits, 64, 441);
  k_softmax<<<NROW, 256, 0, stream>>>(logits, kout);
  k_gather<<<3456, 256, 0, stream>>>(x, logits, out0);
}

// Round 9
// 1119.522 us; speedup vs baseline: 1.0659x; 1.0659x over previous
//
#include <hip/hip_runtime.h>
#include <hip/hip_bf16.h>

#define EPSF 1e-5f
#define BB 2
#define CC 3
#define HH 48
#define WW 48
#define SS 2304
#define DD 64
#define NHH 8
#define FFF 2048
#define NLL 8
#define KS 21
#define PP 441
#define NROW (BB*SS)      // 4608
#define KSPLIT 16
#define KB (SS/KSPLIT)    // 144
#define FFSPLIT 8

typedef __attribute__((ext_vector_type(8))) short s8v;
typedef __attribute__((ext_vector_type(4))) float f4v;
typedef unsigned short ushort_t;

__device__ __forceinline__ ushort_t f2bf(float f) {
  unsigned u = __float_as_uint(f);
  u += 0x7FFFu + ((u >> 16) & 1u);          // round-to-nearest-even
  return (ushort_t)(u >> 16);
}
__device__ __forceinline__ float bf2f(ushort_t h) {
  return __uint_as_float(((unsigned)h) << 16);
}

// ---------------- conv3x3 + batchnorm + relu -> y[b,s,d] ----------------
__global__ __launch_bounds__(256) void k_conv(const float* __restrict__ x,
    const float* __restrict__ cw, const float* __restrict__ cb,
    const float* __restrict__ bng, const float* __restrict__ bnb,
    const float* __restrict__ bnm, const float* __restrict__ bnv,
    float* __restrict__ y)
{
  int tid = blockIdx.x * 256 + threadIdx.x;      // B*S*64 = 294912 threads
  int d = tid & 63;
  int s = (tid >> 6) % SS;
  int b = tid / (SS * 64);
  int h = s / WW, w = s % WW;
  float acc = cb[d];
  #pragma unroll
  for (int c = 0; c < 3; ++c) {
    #pragma unroll
    for (int kh = 0; kh < 3; ++kh) {
      int ih = h + kh - 1;
      if (ih < 0 || ih >= HH) continue;
      #pragma unroll
      for (int kw = 0; kw < 3; ++kw) {
        int iw = w + kw - 1;
        if (iw < 0 || iw >= WW) continue;
        acc = fmaf(x[((b*3 + c)*HH + ih)*WW + iw],
                   cw[((d*3 + c)*3 + kh)*3 + kw], acc);
      }
    }
  }
  acc = (acc - bnm[d]) * rsqrtf(bnv[d] + EPSF) * bng[d] + bnb[d];
  acc = fmaxf(acc, 0.f);
  y[(size_t)(b*SS + s)*DD + d] = acc;
}

// ---- split fp32 array into bf16 hi/lo pair (for split-bf16 MFMA) ----
__global__ __launch_bounds__(256) void k_split(const float* __restrict__ w,
    ushort_t* __restrict__ hi, ushort_t* __restrict__ lo, int n)
{
  int i = blockIdx.x * 256 + threadIdx.x;
  if (i >= n) return;
  float v = w[i];
  ushort_t h = f2bf(v);
  hi[i] = h;
  lo[i] = f2bf(v - bf2f(h));
}

// ------- 32-row-tile GEMM: out[n,j] = bias[j] + sum_k A[n,k]*W[j,k] -------
__global__ __launch_bounds__(256) void k_gemm32(const float* __restrict__ A,
    const float* __restrict__ Wt, const float* __restrict__ bias,
    float* __restrict__ out, int K, int J)
{
  __shared__ float As[64][36];   // As[k][m], m in 0..31
  __shared__ float Ws[64][68];   // Ws[k][j]
  int tid = threadIdx.x;
  int m0 = blockIdx.x * 32;
  int j0 = blockIdx.y * 64;
  int tx = tid & 15, ty = tid >> 4;
  float acc[2][4] = {};
  for (int k0 = 0; k0 < K; k0 += 64) {
    #pragma unroll
    for (int i = 0; i < 8; ++i) {
      int idx = tid + i * 256;
      int m = idx >> 6, k = idx & 63;
      As[k][m] = A[(size_t)(m0 + m) * K + k0 + k];
    }
    #pragma unroll
    for (int i = 0; i < 16; ++i) {
      int idx = tid + i * 256;
      int j = idx >> 6, k = idx & 63;
      int jj = j0 + j;
      Ws[k][j] = (jj < J) ? Wt[(size_t)jj * K + k0 + k] : 0.f;
    }
    __syncthreads();
    #pragma unroll 8
    for (int k = 0; k < 64; ++k) {
      float2 af = *(const float2*)&As[k][ty * 2];
      float4 wf = *(const float4*)&Ws[k][tx * 4];
      float a[2] = {af.x, af.y};
      float w[4] = {wf.x, wf.y, wf.z, wf.w};
      #pragma unroll
      for (int i = 0; i < 2; ++i)
        #pragma unroll
        for (int j = 0; j < 4; ++j)
          acc[i][j] = fmaf(a[i], w[j], acc[i][j]);
    }
    __syncthreads();
  }
  #pragma unroll
  for (int i = 0; i < 2; ++i) {
    int m = m0 + ty * 2 + i;
    #pragma unroll
    for (int j = 0; j < 4; ++j) {
      int jj = j0 + tx * 4 + j;
      if (jj >= J) continue;
      out[(size_t)m * J + jj] = acc[i][j] + bias[jj];
    }
  }
}

// -- out-proj GEMM fused with residual + LN1; also emits y hi/lo bf16 --
__global__ __launch_bounds__(256) void k_oproj_ln(const float* __restrict__ o,
    const float* __restrict__ Wt, const float* __restrict__ bias,
    float* __restrict__ y, const float* __restrict__ g, const float* __restrict__ bb,
    ushort_t* __restrict__ yh, ushort_t* __restrict__ yl)
{
  __shared__ float As[64][36];   // As[k][m] = o[m0+m][k]
  __shared__ float Ws[64][68];   // Ws[k][j] = Wt[j][k]
  int tid = threadIdx.x;
  int m0 = blockIdx.x * 32;
  int tx = tid & 15, ty = tid >> 4;
  #pragma unroll
  for (int i = 0; i < 8; ++i) {
    int idx = tid + i * 256;
    int m = idx >> 6, k = idx & 63;
    As[k][m] = o[(size_t)(m0 + m) * DD + k];
  }
  #pragma unroll
  for (int i = 0; i < 16; ++i) {
    int idx = tid + i * 256;
    int j = idx >> 6, k = idx & 63;
    Ws[k][j] = Wt[(size_t)j * DD + k];
  }
  __syncthreads();
  float acc[2][4] = {};
  #pragma unroll 8
  for (int k = 0; k < 64; ++k) {
    float2 af = *(const float2*)&As[k][ty * 2];
    float4 wf = *(const float4*)&Ws[k][tx * 4];
    float a[2] = {af.x, af.y};
    float w[4] = {wf.x, wf.y, wf.z, wf.w};
    #pragma unroll
    for (int i = 0; i < 2; ++i)
      #pragma unroll
      for (int j = 0; j < 4; ++j)
        acc[i][j] = fmaf(a[i], w[j], acc[i][j]);
  }
  float4 gv = *(const float4*)&g[tx * 4];
  float4 bv = *(const float4*)&bb[tx * 4];
  float4 biv = *(const float4*)&bias[tx * 4];
  float gg[4] = {gv.x, gv.y, gv.z, gv.w};
  float bbv[4] = {bv.x, bv.y, bv.z, bv.w};
  float bi[4] = {biv.x, biv.y, biv.z, biv.w};
  #pragma unroll
  for (int i = 0; i < 2; ++i) {
    int m = m0 + ty * 2 + i;
    float4 yv = *(const float4*)&y[(size_t)m * DD + tx * 4];
    float yr[4] = {yv.x, yv.y, yv.z, yv.w};
    float z[4], s = 0.f, ss = 0.f;
    #pragma unroll
    for (int j = 0; j < 4; ++j) {
      float v = acc[i][j] + bi[j] + yr[j];
      z[j] = v; s += v; ss = fmaf(v, v, ss);
    }
    #pragma unroll
    for (int off = 1; off < 16; off <<= 1) {
      s  += __shfl_xor(s, off);
      ss += __shfl_xor(ss, off);
    }
    float mean = s * 0.015625f;
    float var = ss * 0.015625f - mean * mean;
    float inv = rsqrtf(var + EPSF);
    float ov[4];
    #pragma unroll
    for (int j = 0; j < 4; ++j)
      ov[j] = (z[j] - mean) * inv * gg[j] + bbv[j];
    *(float4*)&y[(size_t)m * DD + tx * 4] = make_float4(ov[0], ov[1], ov[2], ov[3]);
    size_t yb = (size_t)m * DD + tx * 4;
    #pragma unroll
    for (int j = 0; j < 4; ++j) {
      ushort_t h = f2bf(ov[j]);
      yh[yb + j] = h;
      yl[yb + j] = f2bf(ov[j] - bf2f(h));
    }
  }
}

// ---- fused FF via split-bf16 MFMA: pff[split] = relu(y@W1^T+b1)@W2^T ----
// grid (72, FFSPLIT); 4 independent waves/block (16 rows each), no barriers.
__global__ __launch_bounds__(256) void k_ff(const ushort_t* __restrict__ yh,
    const ushort_t* __restrict__ yl,
    const ushort_t* __restrict__ w1h, const ushort_t* __restrict__ w1l,
    const float* __restrict__ b1,
    const ushort_t* __restrict__ w2h, const ushort_t* __restrict__ w2l,
    float* __restrict__ pff)
{
  __shared__ float Hs[64][68];   // per-wave-private 16-row slices
  int tid = threadIdx.x;
  int w = tid >> 6, lane = tid & 63;
  int laneR = lane & 15, laneQ = lane >> 4;
  int m0 = blockIdx.x * 64;
  int split = blockIdx.y;

  // A1 fragments (y rows, K=64): reused across all chunks
  size_t ybase = (size_t)(m0 + w * 16 + laneR) * DD + laneQ * 8;
  s8v a1h0 = *(const s8v*)(yh + ybase);
  s8v a1h1 = *(const s8v*)(yh + ybase + 32);
  s8v a1l0 = *(const s8v*)(yl + ybase);
  s8v a1l1 = *(const s8v*)(yl + ybase + 32);

  f4v acc2[4];
  #pragma unroll
  for (int nt = 0; nt < 4; ++nt) acc2[nt] = (f4v){0.f, 0.f, 0.f, 0.f};

  for (int c = 0; c < FFF / FFSPLIT / 64; ++c) {
    int ff0 = split * (FFF / FFSPLIT) + c * 64;
    // ---- GEMM1: H[16m x 64ff] = y @ W1^T, 4 n-tiles ----
    #pragma unroll
    for (int nt = 0; nt < 4; ++nt) {
      size_t wb = (size_t)(ff0 + nt * 16 + laneR) * DD + laneQ * 8;
      s8v b0h = *(const s8v*)(w1h + wb);
      s8v b0l = *(const s8v*)(w1l + wb);
      s8v b1h_ = *(const s8v*)(w1h + wb + 32);
      s8v b1l_ = *(const s8v*)(w1l + wb + 32);
      f4v acc = (f4v){0.f, 0.f, 0.f, 0.f};
      acc = __builtin_amdgcn_mfma_f32_16x16x32_bf16(a1h0, b0h, acc, 0, 0, 0);
      acc = __builtin_amdgcn_mfma_f32_16x16x32_bf16(a1h0, b0l, acc, 0, 0, 0);
      acc = __builtin_amdgcn_mfma_f32_16x16x32_bf16(a1l0, b0h, acc, 0, 0, 0);
      acc = __builtin_amdgcn_mfma_f32_16x16x32_bf16(a1h1, b1h_, acc, 0, 0, 0);
      acc = __builtin_amdgcn_mfma_f32_16x16x32_bf16(a1h1, b1l_, acc, 0, 0, 0);
      acc = __builtin_amdgcn_mfma_f32_16x16x32_bf16(a1l1, b1h_, acc, 0, 0, 0);
      float bj = b1[ff0 + nt * 16 + laneR];
      #pragma unroll
      for (int r = 0; r < 4; ++r)
        Hs[w * 16 + laneQ * 4 + r][nt * 16 + laneR] = fmaxf(acc[r] + bj, 0.f);
    }
    // ---- A2 fragments from Hs (wave-private rows; in-order LDS) ----
    s8v a2h[2], a2l[2];
    #pragma unroll
    for (int t = 0; t < 2; ++t) {
      const float* hp = &Hs[w * 16 + laneR][t * 32 + laneQ * 8];
      float4 h0 = *(const float4*)hp;
      float4 h1 = *(const float4*)(hp + 4);
      float tv[8] = {h0.x, h0.y, h0.z, h0.w, h1.x, h1.y, h1.z, h1.w};
      #pragma unroll
      for (int j = 0; j < 8; ++j) {
        ushort_t hb = f2bf(tv[j]);
        a2h[t][j] = (short)hb;
        a2l[t][j] = (short)f2bf(tv[j] - bf2f(hb));
      }
    }
    // ---- GEMM2: acc2 += H @ W2^T(chunk), 4 n-tiles ----
    #pragma unroll
    for (int nt = 0; nt < 4; ++nt) {
      size_t wb = (size_t)(nt * 16 + laneR) * FFF + ff0 + laneQ * 8;
      s8v b0h = *(const s8v*)(w2h + wb);
      s8v b0l = *(const s8v*)(w2l + wb);
      s8v b1h_ = *(const s8v*)(w2h + wb + 32);
      s8v b1l_ = *(const s8v*)(w2l + wb + 32);
      acc2[nt] = __builtin_amdgcn_mfma_f32_16x16x32_bf16(a2h[0], b0h, acc2[nt], 0, 0, 0);
      acc2[nt] = __builtin_amdgcn_mfma_f32_16x16x32_bf16(a2h[0], b0l, acc2[nt], 0, 0, 0);
      acc2[nt] = __builtin_amdgcn_mfma_f32_16x16x32_bf16(a2l[0], b0h, acc2[nt], 0, 0, 0);
      acc2[nt] = __builtin_amdgcn_mfma_f32_16x16x32_bf16(a2h[1], b1h_, acc2[nt], 0, 0, 0);
      acc2[nt] = __builtin_amdgcn_mfma_f32_16x16x32_bf16(a2h[1], b1l_, acc2[nt], 0, 0, 0);
      acc2[nt] = __builtin_amdgcn_mfma_f32_16x16x32_bf16(a2l[1], b1h_, acc2[nt], 0, 0, 0);
    }
  }
  // ---- write partials (D-layout: row = laneQ*4+r, col = laneR) ----
  #pragma unroll
  for (int nt = 0; nt < 4; ++nt) {
    #pragma unroll
    for (int r = 0; r < 4; ++r) {
      int m = m0 + w * 16 + laneQ * 4 + r;
      pff[((size_t)split * NROW + m) * DD + nt * 16 + laneR] = acc2[nt][r];
    }
  }
}

// ---- reduce FF partials + b2 + residual + LayerNorm2, one wave per row ----
__global__ __launch_bounds__(256) void k_ff_reduce(const float* __restrict__ pff,
    const float* __restrict__ b2, float* __restrict__ y,
    const float* __restrict__ g, const float* __restrict__ bb)
{
  int lane = threadIdx.x & 63;
  int row = blockIdx.x * 4 + (threadIdx.x >> 6);
  float f = b2[lane];
  #pragma unroll
  for (int sp = 0; sp < FFSPLIT; ++sp)
    f += pff[((size_t)sp * NROW + row) * DD + lane];
  size_t base = (size_t)row * DD + lane;
  float z = y[base] + f;
  float s = z;
  #pragma unroll
  for (int off = 32; off; off >>= 1) s += __shfl_xor(s, off);
  float mean = s * 0.015625f;
  float dz = z - mean;
  float sq = dz * dz;
  #pragma unroll
  for (int off = 32; off; off >>= 1) sq += __shfl_xor(sq, off);
  float var = sq * 0.015625f;
  y[base] = dz * rsqrtf(var + EPSF) * g[lane] + bb[lane];
}

// ------- split-K attention, branchless (|scores| ~ O(1)), 3 queries/thread ----
__global__ __launch_bounds__(256) void k_attn(const float* __restrict__ qkv,
    float* __restrict__ pl, float* __restrict__ pacc)
{
  int bh = blockIdx.x; int b = bh >> 3; int hh = bh & 7;
  int split = blockIdx.z;
  __shared__ float kl[KB][8];
  __shared__ float vl[KB][8];
  int tid = threadIdx.x;
  for (int t = tid; t < KB * 4; t += 256) {
    int row = t >> 2, seg = t & 3;
    const float* base = qkv + (size_t)(b * SS + split * KB + row) * 192 + hh * 8;
    if (seg < 2) *(float4*)&kl[row][seg * 4]       = *(const float4*)(base + 64 + seg * 4);
    else         *(float4*)&vl[row][(seg - 2) * 4] = *(const float4*)(base + 128 + (seg - 2) * 4);
  }
  __syncthreads();

  const float sc = 0.3535533905932738f;  // 1/sqrt(8)
  float q[3][8], acc[3][8] = {}, l[3] = {};
  #pragma unroll
  for (int r = 0; r < 3; ++r) {
    int qi = blockIdx.y * 768 + r * 256 + tid;
    const float* qp = qkv + (size_t)(b * SS + qi) * 192 + hh * 8;
    float4 qa = *(const float4*)qp;
    float4 qb = *(const float4*)(qp + 4);
    q[r][0] = qa.x * sc; q[r][1] = qa.y * sc; q[r][2] = qa.z * sc; q[r][3] = qa.w * sc;
    q[r][4] = qb.x * sc; q[r][5] = qb.y * sc; q[r][6] = qb.z * sc; q[r][7] = qb.w * sc;
  }

  #pragma unroll 2
  for (int j = 0; j < KB; ++j) {
    float4 k0 = *(const float4*)&kl[j][0];
    float4 k1 = *(const float4*)&kl[j][4];
    float4 v0 = *(const float4*)&vl[j][0];
    float4 v1 = *(const float4*)&vl[j][4];
    #pragma unroll
    for (int r = 0; r < 3; ++r) {
      float s = q[r][0] * k0.x;
      s = fmaf(q[r][1], k0.y, s); s = fmaf(q[r][2], k0.z, s); s = fmaf(q[r][3], k0.w, s);
      s = fmaf(q[r][4], k1.x, s); s = fmaf(q[r][5], k1.y, s);
      s = fmaf(q[r][6], k1.z, s); s = fmaf(q[r][7], k1.w, s);
      float p = __expf(s);
      l[r] += p;
      acc[r][0] = fmaf(p, v0.x, acc[r][0]); acc[r][1] = fmaf(p, v0.y, acc[r][1]);
      acc[r][2] = fmaf(p, v0.z, acc[r][2]); acc[r][3] = fmaf(p, v0.w, acc[r][3]);
      acc[r][4] = fmaf(p, v1.x, acc[r][4]); acc[r][5] = fmaf(p, v1.y, acc[r][5]);
      acc[r][6] = fmaf(p, v1.z, acc[r][6]); acc[r][7] = fmaf(p, v1.w, acc[r][7]);
    }
  }
  #pragma unroll
  for (int r = 0; r < 3; ++r) {
    int qi = blockIdx.y * 768 + r * 256 + tid;
    size_t pidx = ((size_t)split * 16 + bh) * SS + qi;
    pl[pidx] = l[r];
    float4* pa = (float4*)(pacc + pidx * 8);
    pa[0] = make_float4(acc[r][0], acc[r][1], acc[r][2], acc[r][3]);
    pa[1] = make_float4(acc[r][4], acc[r][5], acc[r][6], acc[r][7]);
  }
}

__global__ __launch_bounds__(256) void k_attn_combine(const float* __restrict__ pl,
    const float* __restrict__ pacc, float* __restrict__ o)
{
  int idx = blockIdx.x * 256 + threadIdx.x;   // 16*2304 = 36864
  int bh = idx / SS; int qi = idx % SS;
  int b = bh >> 3, hh = bh & 7;
  float L = 0.f, acc[8] = {};
  #pragma unroll
  for (int sp = 0; sp < KSPLIT; ++sp) {
    size_t pidx = ((size_t)sp * 16 + bh) * SS + qi;
    L += pl[pidx];
    const float4* pa = (const float4*)(pacc + pidx * 8);
    float4 a0 = pa[0], a1 = pa[1];
    acc[0] += a0.x; acc[1] += a0.y; acc[2] += a0.z; acc[3] += a0.w;
    acc[4] += a1.x; acc[5] += a1.y; acc[6] += a1.z; acc[7] += a1.w;
  }
  float inv = 1.f / L;
  float* op = o + (size_t)(b * SS + qi) * DD + hh * 8;
  #pragma unroll
  for (int d = 0; d < 8; ++d) op[d] = acc[d] * inv;
}

// ---------------- softmax over 441 logits; probs fp32 in-place + fp32 kernel_out^T
__global__ __launch_bounds__(256) void k_softmax(float* __restrict__ logits,
    float* __restrict__ kout)
{
  __shared__ float red[8];
  int row = blockIdx.x;               // b*S + s
  int b = row / SS, s = row % SS;
  float* lp = logits + (size_t)row * PP;
  int t = threadIdx.x;
  float v0 = (t < PP) ? lp[t] : -1e30f;
  float v1 = (t + 256 < PP) ? lp[t + 256] : -1e30f;
  float mx = fmaxf(v0, v1);
  #pragma unroll
  for (int off = 32; off; off >>= 1) mx = fmaxf(mx, __shfl_xor(mx, off));
  if ((t & 63) == 0) red[t >> 6] = mx;
  __syncthreads();
  mx = fmaxf(fmaxf(red[0], red[1]), fmaxf(red[2], red[3]));
  float e0 = (t < PP) ? __expf(v0 - mx) : 0.f;
  float e1 = (t + 256 < PP) ? __expf(v1 - mx) : 0.f;
  float sm = e0 + e1;
  #pragma unroll
  for (int off = 32; off; off >>= 1) sm += __shfl_xor(sm, off);
  if ((t & 63) == 0) red[4 + (t >> 6)] = sm;
  __syncthreads();
  float inv = 1.f / (red[4] + red[5] + red[6] + red[7]);
  if (t < PP) {
    float p = e0 * inv;
    lp[t] = p;
    kout[(size_t)(b * PP + t) * SS + s] = p;
  }
  if (t + 256 < PP) {
    float p = e1 * inv;
    lp[t + 256] = p;
    kout[(size_t)(b * PP + t + 256) * SS + s] = p;
  }
}

// ------- final 21x21 reflect-padded gather: one wave per output pixel -------
__global__ __launch_bounds__(256) void k_gather(const float* __restrict__ x,
    const float* __restrict__ probs, float* __restrict__ out)
{
  int lane = threadIdx.x & 63;
  int pix = blockIdx.x * 4 + (threadIdx.x >> 6);  // 0..13823
  int w = pix % WW;
  int h = (pix / WW) % HH;
  int c = (pix / (WW * HH)) % CC;
  int b = pix / (WW * HH * CC);
  int s = h * WW + w;
  const float* pp = probs + (size_t)(b * SS + s) * PP;
  const float* xb = x + (size_t)(b * CC + c) * HH * WW;
  float acc = 0.f;
  for (int t = lane; t < PP; t += 64) {
    int kr = t / KS, kc = t - kr * KS;
    int ih = h + kr - 10;
    ih = (ih < 0) ? -ih : (ih > 47 ? 94 - ih : ih);
    int iw = w + kc - 10;
    iw = (iw < 0) ? -iw : (iw > 47 ? 94 - iw : iw);
    acc = fmaf(xb[ih * WW + iw], pp[t], acc);
  }
  #pragma unroll
  for (int off = 32; off; off >>= 1) acc += __shfl_xor(acc, off);
  if (lane == 0) out[pix] = acc;
}

extern "C" void kernel_launch(void* const* d_in, const int* in_sizes, int n_in,
                              void* d_out, int out_size, void* d_ws, size_t ws_size,
                              hipStream_t stream)
{
  (void)in_sizes; (void)n_in; (void)out_size; (void)ws_size;
  const float* x       = (const float*)d_in[0];
  const float* conv1_w = (const float*)d_in[1];
  const float* conv1_b = (const float*)d_in[2];
  const float* bn_g    = (const float*)d_in[3];
  const float* bn_b    = (const float*)d_in[4];
  const float* bn_m    = (const float*)d_in[5];
  const float* bn_v    = (const float*)d_in[6];
  const float* w_in    = (const float*)d_in[7];
  const float* b_in    = (const float*)d_in[8];
  const float* w_out   = (const float*)d_in[9];
  const float* b_out   = (const float*)d_in[10];
  const float* w1      = (const float*)d_in[11];
  const float* b1      = (const float*)d_in[12];
  const float* w2      = (const float*)d_in[13];
  const float* b2      = (const float*)d_in[14];
  const float* ln1g    = (const float*)d_in[15];
  const float* ln1b    = (const float*)d_in[16];
  const float* ln2g    = (const float*)d_in[17];
  const float* ln2b    = (const float*)d_in[18];
  const float* lw      = (const float*)d_in[19];
  const float* lb      = (const float*)d_in[20];

  // workspace: ~36.7 MiB
  float* y    = (float*)d_ws;        // 294912
  float* qkv  = y + 294912;          // 884736
  float* o    = qkv + 884736;        // 294912
  float* sc   = o + 294912;          // union region: 4718592 floats
  float* pacc = sc;                  // attn acc partials: 16*16*2304*8
  float* pff  = sc;                  // FF partials: 8*4608*64 = 2359296
  float* logits = sc;                // 4608*441 = 2032128
  float* pl   = sc + 4718592;        // attn l partials: 16*16*2304 = 589824
  ushort_t* yh  = (ushort_t*)(pl + 589824);        // 294912 bf16 (147456 slots)
  ushort_t* yl  = (ushort_t*)(pl + 589824 + 147456);
  ushort_t* w1h = (ushort_t*)(pl + 589824 + 294912);             // 1048576 bf16 each
  ushort_t* w1l = (ushort_t*)(pl + 589824 + 294912 + 524288);
  ushort_t* w2h = (ushort_t*)(pl + 589824 + 294912 + 1048576);
  ushort_t* w2l = (ushort_t*)(pl + 589824 + 294912 + 1572864);

  float* out0 = (float*)d_out;
  float* kout = out0 + (size_t)BB * CC * HH * WW;

  // pre-split FF weights to bf16 hi/lo (all layers)
  k_split<<<4096, 256, 0, stream>>>(w1, w1h, w1l, NLL * FFF * DD);
  k_split<<<4096, 256, 0, stream>>>(w2, w2h, w2l, NLL * FFF * DD);

  k_conv<<<1152, 256, 0, stream>>>(x, conv1_w, conv1_b, bn_g, bn_b, bn_m, bn_v, y);

  for (int l = 0; l < NLL; ++l) {
    k_gemm32<<<dim3(144, 3), 256, 0, stream>>>(y, w_in + (size_t)l * 192 * 64,
        b_in + l * 192, qkv, 64, 192);
    k_attn<<<dim3(16, 3, KSPLIT), 256, 0, stream>>>(qkv, pl, pacc);
    k_attn_combine<<<144, 256, 0, stream>>>(pl, pacc, o);
    k_oproj_ln<<<144, 256, 0, stream>>>(o, w_out + (size_t)l * 64 * 64,
        b_out + l * 64, y, ln1g + l * 64, ln1b + l * 64, yh, yl);
    k_ff<<<dim3(72, FFSPLIT), 256, 0, stream>>>(yh, yl,
        w1h + (size_t)l * FFF * DD, w1l + (size_t)l * FFF * DD, b1 + (size_t)l * FFF,
        w2h + (size_t)l * FFF * DD, w2l + (size_t)l * FFF * DD, pff);
    k_ff_reduce<<<1152, 256, 0, stream>>>(pff, b2 + l * DD, y,
        ln2g + l * 64, ln2b + l * 64);
  }

  k_gemm32<<<dim3(144, 7), 256, 0, stream>>>(y, lw, lb, logits, 64, 441);
  k_softmax<<<NROW, 256, 0, stream>>>(logits, kout);
  k_gather<<<3456, 256, 0, stream>>>(x, logits, out0);
}